// Round 1
// baseline (1667.835 us; speedup 1.0000x reference)
//
#include <hip/hip_runtime.h>
#include <math.h>

#define B_ 2
#define T_ 512
#define DM_ 1024
#define DH_ 4096
#define DD_ 4
#define V_ 32000
#define M_ 4096      // B*T*DD
#define BT_ 1024     // B*T

typedef __attribute__((ext_vector_type(8))) unsigned short ushort8_t;
typedef __attribute__((ext_vector_type(4))) unsigned short ushort4_t;
typedef __attribute__((ext_vector_type(8))) __bf16 bf16x8;
typedef __attribute__((ext_vector_type(4))) float f32x4;

__device__ __forceinline__ unsigned short f2bf(float x) {
  union { float f; unsigned u; } v; v.f = x;
  unsigned r = v.u + 0x7fffu + ((v.u >> 16) & 1u);
  return (unsigned short)(r >> 16);
}
__device__ __forceinline__ float bf2f(unsigned short h) {
  union { unsigned u; float f; } v; v.u = ((unsigned)h) << 16; return v.f;
}

__device__ __forceinline__ float block_sum256(float v, float* sh) {
  #pragma unroll
  for (int o = 32; o >= 1; o >>= 1) v += __shfl_down(v, o);
  int lane = threadIdx.x & 63, wid = threadIdx.x >> 6;
  if (lane == 0) sh[wid] = v;
  __syncthreads();
  float t = sh[0] + sh[1] + sh[2] + sh[3];
  __syncthreads();
  return t;
}
__device__ __forceinline__ float block_max256(float v, float* sh) {
  #pragma unroll
  for (int o = 32; o >= 1; o >>= 1) v = fmaxf(v, __shfl_down(v, o));
  int lane = threadIdx.x & 63, wid = threadIdx.x >> 6;
  if (lane == 0) sh[wid] = v;
  __syncthreads();
  float t = fmaxf(fmaxf(sh[0], sh[1]), fmaxf(sh[2], sh[3]));
  __syncthreads();
  return t;
}

// Transpose f32 (R,C) -> split bf16 hi/lo (C,R). lo may be null.
__global__ __launch_bounds__(256) void transpose_split_kernel(
    const float* __restrict__ in, int R, int C,
    unsigned short* __restrict__ out_hi, unsigned short* __restrict__ out_lo)
{
  __shared__ float tile[32][33];
  int c0 = blockIdx.x * 32, r0 = blockIdx.y * 32;
  int tx = threadIdx.x & 31, ty = threadIdx.x >> 5;   // 32 x 8
  #pragma unroll
  for (int i = 0; i < 4; ++i)
    tile[ty + i * 8][tx] = in[(size_t)(r0 + ty + i * 8) * C + c0 + tx];
  __syncthreads();
  #pragma unroll
  for (int i = 0; i < 4; ++i) {
    int orow = c0 + ty + i * 8;
    int ocol = r0 + tx;
    float v = tile[tx][ty + i * 8];
    unsigned short h = f2bf(v);
    out_hi[(size_t)orow * R + ocol] = h;
    if (out_lo) out_lo[(size_t)orow * R + ocol] = f2bf(v - bf2f(h));
  }
}

// Per-row embed + LayerNorm -> split bf16 X (M, DM)
__global__ __launch_bounds__(256) void embed_ln_kernel(
    const float* __restrict__ H, const int* __restrict__ ids,
    const float* __restrict__ emb, const float* __restrict__ demb,
    const float* __restrict__ g, const float* __restrict__ be,
    unsigned short* __restrict__ Xhi, unsigned short* __restrict__ Xlo)
{
  __shared__ float sh[8];
  int m = blockIdx.x, tid = threadIdx.x;
  int bt = m >> 2, d = m & 3;
  int id = ids[bt];
  float4 x  = ((const float4*)(H   + (size_t)bt * DM_))[tid];
  float4 e  = ((const float4*)(emb + (size_t)id * DM_))[tid];
  float4 de = ((const float4*)(demb + (size_t)d * DM_))[tid];
  float v0 = x.x + e.x + de.x, v1 = x.y + e.y + de.y;
  float v2 = x.z + e.z + de.z, v3 = x.w + e.w + de.w;
  float mu = block_sum256((v0 + v1) + (v2 + v3), sh) * (1.0f / DM_);
  float d0 = v0 - mu, d1v = v1 - mu, d2 = v2 - mu, d3 = v3 - mu;
  float var = block_sum256((d0 * d0 + d1v * d1v) + (d2 * d2 + d3 * d3), sh) * (1.0f / DM_);
  float rs = rsqrtf(var + 1e-5f);
  float4 gg  = ((const float4*)g)[tid];
  float4 bb4 = ((const float4*)be)[tid];
  float y0 = d0 * rs * gg.x + bb4.x;
  float y1 = d1v * rs * gg.y + bb4.y;
  float y2 = d2 * rs * gg.z + bb4.z;
  float y3 = d3 * rs * gg.w + bb4.w;
  unsigned short h0 = f2bf(y0), h1 = f2bf(y1), h2 = f2bf(y2), h3 = f2bf(y3);
  ushort4_t hv = {h0, h1, h2, h3};
  ushort4_t lv = {f2bf(y0 - bf2f(h0)), f2bf(y1 - bf2f(h1)), f2bf(y2 - bf2f(h2)), f2bf(y3 - bf2f(h3))};
  size_t base = (size_t)m * DM_ + tid * 4;
  *(ushort4_t*)&Xhi[base] = hv;
  *(ushort4_t*)&Xlo[base] = lv;
}

// w2b[j] = sum_i W2[j,i]*Wb[i]  (j<DH) ; w2b[DH] = b2.Wb + bb
__global__ __launch_bounds__(64) void w2b_kernel(
    const float* __restrict__ W2, const float* __restrict__ Wb,
    const float* __restrict__ b2, const float* __restrict__ bb,
    float* __restrict__ w2b)
{
  int j = blockIdx.x, lane = threadIdx.x;
  const float* rowp = (j < DH_) ? (W2 + (size_t)j * DM_) : b2;
  const float4* r4 = (const float4*)rowp;
  const float4* w4 = (const float4*)Wb;
  float s = 0.0f;
  for (int i = lane; i < DM_ / 4; i += 64) {
    float4 a = r4[i], w = w4[i];
    s += a.x * w.x + a.y * w.y + a.z * w.z + a.w * w.w;
  }
  #pragma unroll
  for (int o = 32; o >= 1; o >>= 1) s += __shfl_down(s, o);
  if (lane == 0) w2b[j] = (j < DH_) ? s : (s + bb[0]);
}

// C = A @ B^T_stored(+bias)(+GELU) with A (M,K) bf16 hi/lo and B (N,K) bf16 hi/lo.
// SPLIT: 4-term hi/lo product (~f32 accuracy). Outputs optional: f32, bf16 hi, bf16 lo.
template<bool SPLIT, bool GELU>
__global__ __launch_bounds__(256) void gemm_kernel(
    const unsigned short* __restrict__ Ahi, const unsigned short* __restrict__ Alo,
    const unsigned short* __restrict__ Bhi, const unsigned short* __restrict__ Blo,
    const float* __restrict__ bias, int Ndim, int Kdim,
    float* __restrict__ Cf, unsigned short* __restrict__ Chi, unsigned short* __restrict__ Clo,
    const int* __restrict__ rowmask)
{
  constexpr int LDT = 40;  // padded LDS stride (bf16 elems): 80B rows -> conflict-light
  __shared__ __align__(16) unsigned short sAhi[128 * LDT];
  __shared__ __align__(16) unsigned short sBhi[128 * LDT];
  __shared__ __align__(16) unsigned short sAlo[SPLIT ? 128 * LDT : 8];
  __shared__ __align__(16) unsigned short sBlo[SPLIT ? 128 * LDT : 8];
  const int n0 = blockIdx.x * 128, m0 = blockIdx.y * 128;
  const int tid = threadIdx.x, lane = tid & 63, wid = tid >> 6;
  const int wr = wid >> 1, wc = wid & 1;
  const int lrow = lane & 15, koff = (lane >> 4) * 8;
  const int rr = tid >> 2, cc = (tid & 3) * 8;

  f32x4 acc[4][4] = {};

  for (int k0 = 0; k0 < Kdim; k0 += 32) {
    __syncthreads();
    #pragma unroll
    for (int ch = 0; ch < 2; ++ch) {
      int r = rr + ch * 64;
      size_t ga = (size_t)(m0 + r) * Kdim + (k0 + cc);
      size_t gb = (size_t)(n0 + r) * Kdim + (k0 + cc);
      *(ushort8_t*)&sAhi[r * LDT + cc] = *(const ushort8_t*)&Ahi[ga];
      *(ushort8_t*)&sBhi[r * LDT + cc] = *(const ushort8_t*)&Bhi[gb];
      if constexpr (SPLIT) {
        *(ushort8_t*)&sAlo[r * LDT + cc] = *(const ushort8_t*)&Alo[ga];
        *(ushort8_t*)&sBlo[r * LDT + cc] = *(const ushort8_t*)&Blo[gb];
      }
    }
    __syncthreads();
    bf16x8 ah[4], bh[4], al[4], bl[4];
    #pragma unroll
    for (int i = 0; i < 4; ++i) {
      ah[i] = __builtin_bit_cast(bf16x8, *(const ushort8_t*)&sAhi[(wr * 64 + i * 16 + lrow) * LDT + koff]);
      bh[i] = __builtin_bit_cast(bf16x8, *(const ushort8_t*)&sBhi[(wc * 64 + i * 16 + lrow) * LDT + koff]);
      if constexpr (SPLIT) {
        al[i] = __builtin_bit_cast(bf16x8, *(const ushort8_t*)&sAlo[(wr * 64 + i * 16 + lrow) * LDT + koff]);
        bl[i] = __builtin_bit_cast(bf16x8, *(const ushort8_t*)&sBlo[(wc * 64 + i * 16 + lrow) * LDT + koff]);
      }
    }
    #pragma unroll
    for (int mi = 0; mi < 4; ++mi)
      #pragma unroll
      for (int ni = 0; ni < 4; ++ni) {
        acc[mi][ni] = __builtin_amdgcn_mfma_f32_16x16x32_bf16(ah[mi], bh[ni], acc[mi][ni], 0, 0, 0);
        if constexpr (SPLIT) {
          acc[mi][ni] = __builtin_amdgcn_mfma_f32_16x16x32_bf16(ah[mi], bl[ni], acc[mi][ni], 0, 0, 0);
          acc[mi][ni] = __builtin_amdgcn_mfma_f32_16x16x32_bf16(al[mi], bh[ni], acc[mi][ni], 0, 0, 0);
          acc[mi][ni] = __builtin_amdgcn_mfma_f32_16x16x32_bf16(al[mi], bl[ni], acc[mi][ni], 0, 0, 0);
        }
      }
  }

  #pragma unroll
  for (int mi = 0; mi < 4; ++mi) {
    #pragma unroll
    for (int ni = 0; ni < 4; ++ni) {
      int rbase = m0 + wr * 64 + mi * 16 + (lane >> 4) * 4;
      int col = n0 + wc * 64 + ni * 16 + (lane & 15);
      float bv = bias ? bias[col] : 0.0f;
      #pragma unroll
      for (int r2 = 0; r2 < 4; ++r2) {
        int gm = rbase + r2;
        float v = acc[mi][ni][r2] + bv;
        if constexpr (GELU) v = 0.5f * v * (1.0f + erff(v * 0.70710678118654752440f));
        if (rowmask) v *= (rowmask[gm >> 2] ? 1.0f : 0.0f);
        size_t idx = (size_t)gm * Ndim + col;
        if (Cf) Cf[idx] = v;
        if (Chi) {
          unsigned short h = f2bf(v);
          Chi[idx] = h;
          if (Clo) Clo[idx] = f2bf(v - bf2f(h));
        }
      }
    }
  }
}

// beta (from f32 act @ w2b), k, bce, valid flags
__global__ __launch_bounds__(256) void beta_k_kernel(
    const float* __restrict__ act, const float* __restrict__ w2b,
    const int* __restrict__ mask,
    float* __restrict__ beta_out, float* __restrict__ k_out,
    float* __restrict__ bce, int* __restrict__ validf)
{
  __shared__ float sh[8];
  int m = blockIdx.x, tid = threadIdx.x;
  const float4* a4 = (const float4*)(act + (size_t)m * DH_);
  const float4* w4 = (const float4*)w2b;
  float s = 0.0f;
  for (int i = tid; i < DH_ / 4; i += 256) {
    float4 a = a4[i], w = w4[i];
    s += a.x * w.x + a.y * w.y + a.z * w.z + a.w * w.w;
  }
  float tot = block_sum256(s, sh);
  if (tid == 0) {
    int bt = m >> 2, d1 = (m & 3) + 1;
    float beta = tot + w2b[DH_];
    int mv = mask[bt];
    float bm = mv ? beta : 0.0f;
    int t = bt % T_;
    int valid = (t + d1 < T_) && mv && mask[bt + d1];
    beta_out[m] = bm;
    float sp = fmaxf(bm, 0.0f) + log1pf(expf(-fabsf(bm)));
    bce[m] = sp - (valid ? bm : 0.0f);
    validf[m] = valid;
    float sig = 1.0f / (1.0f + expf(-bm));
    int kk = (int)ceilf(sig * 8.0f);
    kk = kk < 1 ? 1 : (kk > 8 ? 8 : kk);
    if (!(sig >= 0.25f)) kk = 0;
    if (!mv) kk = 0;
    k_out[m] = (float)kk;
  }
}

__global__ __launch_bounds__(256) void ce_kernel(
    const float* __restrict__ q, const int* __restrict__ validf,
    const int* __restrict__ labels, float* __restrict__ nll)
{
  __shared__ float sh[8];
  int m = blockIdx.x, tid = threadIdx.x;
  if (!validf[m]) { if (tid == 0) nll[m] = 0.0f; return; }
  int bt = m >> 2, d1 = (m & 3) + 1;
  const float* row = q + (size_t)m * V_;
  float mx = -3.4e38f;
  for (int c = tid; c < V_; c += 256) mx = fmaxf(mx, row[c]);
  mx = block_max256(mx, sh);
  float s = 0.0f;
  for (int c = tid; c < V_; c += 256) s += expf(row[c] - mx);
  s = block_sum256(s, sh);
  if (tid == 0) {
    int tgt = labels[bt + d1];
    nll[m] = -(row[tgt] - mx - logf(s));
  }
}

__global__ __launch_bounds__(256) void loss_kernel(
    const float* __restrict__ nll, const int* __restrict__ validf,
    const float* __restrict__ bce, float* __restrict__ loss_out)
{
  __shared__ float sh[8];
  int tid = threadIdx.x;
  float snll = 0.0f, fcnt = 0.0f, sbce = 0.0f, fnsrc = 0.0f;
  for (int m = tid; m < M_; m += 256) { snll += nll[m]; fcnt += (float)validf[m]; }
  for (int bt = tid; bt < BT_; bt += 256) {
    int base = bt * 4;
    int src = validf[base] | validf[base + 1] | validf[base + 2] | validf[base + 3];
    if (src) { sbce += bce[base] + bce[base + 1] + bce[base + 2] + bce[base + 3]; fnsrc += 1.0f; }
  }
  snll = block_sum256(snll, sh);
  fcnt = block_sum256(fcnt, sh);
  sbce = block_sum256(sbce, sh);
  fnsrc = block_sum256(fnsrc, sh);
  if (tid == 0) {
    float Lq = fcnt > 0.0f ? snll / fcnt : 0.0f;
    float Lb = sbce / fmaxf(fnsrc, 1.0f);
    loss_out[0] = Lq + Lb;
  }
}

extern "C" void kernel_launch(void* const* d_in, const int* in_sizes, int n_in,
                              void* d_out, int out_size, void* d_ws, size_t ws_size,
                              hipStream_t stream) {
  const float* H    = (const float*)d_in[0];
  const int*   ids  = (const int*)d_in[1];
  const int*   mask = (const int*)d_in[2];
  const int*   labels = (const int*)d_in[3];
  const float* emb  = (const float*)d_in[4];
  const float* demb = (const float*)d_in[5];
  const float* ln_g = (const float*)d_in[6];
  const float* ln_b = (const float*)d_in[7];
  const float* W1   = (const float*)d_in[8];
  const float* b1   = (const float*)d_in[9];
  const float* W2   = (const float*)d_in[10];
  const float* b2   = (const float*)d_in[11];
  const float* Wq   = (const float*)d_in[12];
  const float* bq   = (const float*)d_in[13];
  const float* Wb   = (const float*)d_in[14];
  const float* bb   = (const float*)d_in[15];

  char* ws = (char*)d_ws; size_t off = 0;
  auto walloc = [&](size_t bytes) -> void* {
    void* p = ws + off; off = (off + bytes + 255) & ~(size_t)255; return p;
  };
  unsigned short* W1t_hi = (unsigned short*)walloc((size_t)DH_ * DM_ * 2);
  unsigned short* W1t_lo = (unsigned short*)walloc((size_t)DH_ * DM_ * 2);
  unsigned short* W2t_hi = (unsigned short*)walloc((size_t)DM_ * DH_ * 2);
  unsigned short* W2t_lo = (unsigned short*)walloc((size_t)DM_ * DH_ * 2);
  unsigned short* Wqt_hi = (unsigned short*)walloc((size_t)V_ * DM_ * 2);
  unsigned short* Xhi    = (unsigned short*)walloc((size_t)M_ * DM_ * 2);
  unsigned short* Xlo    = (unsigned short*)walloc((size_t)M_ * DM_ * 2);
  unsigned short* S2hi   = (unsigned short*)walloc((size_t)M_ * DM_ * 2);
  float* w2b   = (float*)walloc((DH_ + 1) * 4);
  float* nll   = (float*)walloc(M_ * 4);
  float* bcev  = (float*)walloc(M_ * 4);
  int*   validf = (int*)walloc(M_ * 4);

  float* q_out    = (float*)d_out;
  float* beta_out = q_out + (size_t)M_ * V_;
  float* k_out    = beta_out + M_;
  float* loss_out = k_out + M_;
  // GELU activations live in d_out's q region (overwritten later by q)
  unsigned short* act_hi = (unsigned short*)d_out;
  unsigned short* act_lo = act_hi + (size_t)M_ * DH_;
  float*          act_f  = (float*)(act_lo + (size_t)M_ * DH_);

  // 1) weight transposes + splits
  transpose_split_kernel<<<dim3(DH_ / 32, DM_ / 32), 256, 0, stream>>>(W1, DM_, DH_, W1t_hi, W1t_lo);
  transpose_split_kernel<<<dim3(DM_ / 32, DH_ / 32), 256, 0, stream>>>(W2, DH_, DM_, W2t_hi, W2t_lo);
  transpose_split_kernel<<<dim3(V_ / 32, DM_ / 32), 256, 0, stream>>>(Wq, DM_, V_, Wqt_hi, nullptr);
  // 2) embed + LN
  embed_ln_kernel<<<M_, 256, 0, stream>>>(H, ids, emb, demb, ln_g, ln_b, Xhi, Xlo);
  // 3) w2b fold
  w2b_kernel<<<DH_ + 1, 64, 0, stream>>>(W2, Wb, b2, bb, w2b);
  // 4) GEMM1: act = gelu(X @ W1 + b1)  (split precision)
  gemm_kernel<true, true><<<dim3(DH_ / 128, M_ / 128), 256, 0, stream>>>(
      Xhi, Xlo, W1t_hi, W1t_lo, b1, DH_, DM_, act_f, act_hi, act_lo, nullptr);
  // 5) beta/k/bce from f32 act
  beta_k_kernel<<<M_, 256, 0, stream>>>(act_f, w2b, mask, beta_out, k_out, bcev, validf);
  // 6) GEMM2: S2 = act @ W2 + b2 (split precision, bf16-hi output for q path)
  gemm_kernel<true, false><<<dim3(DM_ / 128, M_ / 128), 256, 0, stream>>>(
      act_hi, act_lo, W2t_hi, W2t_lo, b2, DM_, DH_, nullptr, S2hi, nullptr, nullptr);
  // 7) GEMM3: q = (S2 @ Wq + bq) * mask  (plain bf16)
  gemm_kernel<false, false><<<dim3(V_ / 128, M_ / 128), 256, 0, stream>>>(
      S2hi, nullptr, Wqt_hi, nullptr, bq, V_, DM_, q_out, nullptr, nullptr, mask);
  // 8) CE per row
  ce_kernel<<<M_, 256, 0, stream>>>(q_out, validf, labels, nll);
  // 9) final loss
  loss_kernel<<<1, 256, 0, stream>>>(nll, validf, bcev, loss_out);
}